// Round 9
// baseline (163.178 us; speedup 1.0000x reference)
//
#include <hip/hip_runtime.h>
#include <stdint.h>

#define ALPHA 0.2f

typedef __attribute__((ext_vector_type(8))) short bf16x8;
typedef __attribute__((ext_vector_type(8))) unsigned short u16x8;
typedef __attribute__((ext_vector_type(4))) float f32x4;

__device__ __forceinline__ unsigned short f2bf(float f) {
    unsigned int u = __float_as_uint(f);
    u += 0x7fffu + ((u >> 16) & 1u);   // RNE
    return (unsigned short)(u >> 16);
}

__device__ __forceinline__ void gload_lds16(const void* g, void* l) {
    __builtin_amdgcn_global_load_lds(
        (const __attribute__((address_space(1))) unsigned int*)g,
        (__attribute__((address_space(3))) unsigned int*)l, 16, 0, 0);
}

// ---------------------------------------------------------------------------
// Blocks 0..255: Wtbf[o*256+t] = bf16(W[t*256+o]).
// Block 256:     wa[k] = W[k,:]·a_l ; wa[256+k] = W[k,:]·a_r  (fp32).
// ---------------------------------------------------------------------------
__global__ void wt_wa_kernel(const float* __restrict__ W,
                             const float* __restrict__ a,
                             unsigned short* __restrict__ Wtbf,
                             float* __restrict__ wa) {
    const int t = threadIdx.x;
    if (blockIdx.x < 256) {
        const int o = blockIdx.x;
        Wtbf[o * 256 + t] = f2bf(W[t * 256 + o]);
    } else {
        float sl = 0.f, sr = 0.f;
        const float* wr = W + t * 256;
        for (int o = 0; o < 256; ++o) {
            const float wv = wr[o];
            sl += wv * a[o];
            sr += wv * a[256 + o];
        }
        wa[t] = sl;
        wa[256 + t] = sr;
    }
}

// ---------------------------------------------------------------------------
// gemm_hx: h_T (256 x 16384) = Wtbf @ x^T, reading x fp32 DIRECTLY.
//  - A-panel (64 rows x 256 k bf16, 32 KB) staged ONCE, XOR-swizzled
//    (LDS dest linear for global_load_lds; global chunk c^(r&7)).
//  - K-loop: barrier-free. B-fragments load straight from global x
//    (each wave reads 16 rows x 128 B contiguous per (ks)), RNE-convert
//    to bf16 in-register.
//  - blocks y==0, waves 0/1 also accumulate EXACT fp32 el/er:
//    sl[nt] = sum_k x[row][k]*wa_l[k] per lane over its quad's k-residues,
//    reduced across quads by shfl_xor 16/32.
// Grid (128, 4) = 512 blocks (2/CU).
// ---------------------------------------------------------------------------
__global__ __launch_bounds__(256) void gemm_hx(
    const unsigned short* __restrict__ Wtbf,   // 256 x 256 bf16
    const float* __restrict__ x,               // 16384 x 256 fp32
    const float* __restrict__ wa,              // 512 fp32
    unsigned short* __restrict__ hT,           // 256 x 16384 bf16
    float* __restrict__ el, float* __restrict__ er)
{
    __shared__ __align__(16) unsigned short As[64 * 256];   // 32 KB (swizzled)
    __shared__ float wa_s[512];

    const int tid = threadIdx.x;
    const int w = tid >> 6, l = tid & 63;
    const int q = l >> 4, ml = l & 15;
    const int wm = (w >> 1) * 32;
    const int wn = (w & 1) * 64;
    const int m0 = blockIdx.y * 64;
    const int n0 = blockIdx.x * 128;

    if (tid < 128) *(float4*)(wa_s + tid * 4) = *(const float4*)(wa + tid * 4);

    // stage A panel: 64 rows x 32 chunks(16B) = 2048 chunks, 8 rounds
    for (int rd = 0; rd < 8; ++rd) {
        const int cb = rd * 256 + (w << 6);
        const int p = cb + l;
        const int r = p >> 5;
        const int c = p & 31;
        gload_lds16(Wtbf + (size_t)(m0 + r) * 256 + ((c ^ (r & 7)) << 3),
                    As + cb * 8);
    }
    __syncthreads();

    const bool do_e = (blockIdx.y == 0) && (w < 2);

    f32x4 acc[2][4];
    for (int i = 0; i < 2; ++i)
        for (int j = 0; j < 4; ++j) {
            f32x4 z = {0.f, 0.f, 0.f, 0.f};
            acc[i][j] = z;
        }
    float sl[4] = {0.f, 0.f, 0.f, 0.f};
    float sr[4] = {0.f, 0.f, 0.f, 0.f};

    for (int k0 = 0; k0 < 256; k0 += 64) {
        bf16x8 aF[2][2], bF[2][4];
#pragma unroll
        for (int ks = 0; ks < 2; ++ks) {
            const int kb = k0 + ks * 32 + q * 8;
#pragma unroll
            for (int mt = 0; mt < 2; ++mt) {
                const int row = wm + mt * 16 + ml;
                const int cf = (kb >> 3) ^ (row & 7);
                aF[ks][mt] = *(const bf16x8*)(As + (row * 32 + cf) * 8);
            }
#pragma unroll
            for (int nt = 0; nt < 4; ++nt) {
                const int grow = n0 + wn + nt * 16 + ml;
                const float* xp = x + (size_t)grow * 256 + kb;
                const float4 v0 = *(const float4*)(xp);
                const float4 v1 = *(const float4*)(xp + 4);
                bf16x8 f;
                f[0] = (short)f2bf(v0.x); f[1] = (short)f2bf(v0.y);
                f[2] = (short)f2bf(v0.z); f[3] = (short)f2bf(v0.w);
                f[4] = (short)f2bf(v1.x); f[5] = (short)f2bf(v1.y);
                f[6] = (short)f2bf(v1.z); f[7] = (short)f2bf(v1.w);
                bF[ks][nt] = f;
                if (do_e) {
                    const float* wl = wa_s + kb;
                    const float* wrr = wa_s + 256 + kb;
                    sl[nt] += v0.x * wl[0] + v0.y * wl[1] + v0.z * wl[2] + v0.w * wl[3]
                            + v1.x * wl[4] + v1.y * wl[5] + v1.z * wl[6] + v1.w * wl[7];
                    sr[nt] += v0.x * wrr[0] + v0.y * wrr[1] + v0.z * wrr[2] + v0.w * wrr[3]
                            + v1.x * wrr[4] + v1.y * wrr[5] + v1.z * wrr[6] + v1.w * wrr[7];
                }
            }
        }
#pragma unroll
        for (int ks = 0; ks < 2; ++ks)
            for (int mt = 0; mt < 2; ++mt)
                for (int nt = 0; nt < 4; ++nt)
                    acc[mt][nt] = __builtin_amdgcn_mfma_f32_16x16x32_bf16(
                        aF[ks][mt], bF[ks][nt], acc[mt][nt], 0, 0, 0);
    }

    if (do_e) {
#pragma unroll
        for (int nt = 0; nt < 4; ++nt) {
            sl[nt] += __shfl_xor(sl[nt], 16); sl[nt] += __shfl_xor(sl[nt], 32);
            sr[nt] += __shfl_xor(sr[nt], 16); sr[nt] += __shfl_xor(sr[nt], 32);
        }
        if (l < 16) {
#pragma unroll
            for (int nt = 0; nt < 4; ++nt) {
                const int n = n0 + wn + nt * 16 + l;
                el[n] = sl[nt];
                er[n] = sr[nt];
            }
        }
    }

    // epilogue: D layout col=lane&15, row=(lane>>4)*4+reg
    for (int mt = 0; mt < 2; ++mt)
        for (int nt = 0; nt < 4; ++nt) {
            const int gn = n0 + wn + nt * 16 + ml;
            for (int r = 0; r < 4; ++r) {
                const int gm = m0 + wm + mt * 16 + q * 4 + r;
                hT[(size_t)gm * 16384 + gn] = f2bf(acc[mt][nt][r]);
            }
        }
}

// ---------------------------------------------------------------------------
// pv_fused: mask pre-pass + PV in one kernel.  Grid (32,16) = 512 blocks.
// Pass 1: wave w sweeps rows w*8..w*8+7 of this block's 32 q-rows:
//   online sum s = sum_j adj ? exp(leakyrelu(el_i+er_j)) : 0  (no max pass,
//   logits tiny by construction); bits -> nibs LDS; c_s = log s;
//   repack nibs -> pk_s[32][64].
// Pass 2: R6-proven MFMA j-loop (j-step 64, Hs XOR-swizzled, Ps stride 72),
//   pk/c/el from LDS.  nibs and Ps share one LDS buffer (disjoint phases).
// LDS 49.4 KB -> 3 blocks/CU.
// ---------------------------------------------------------------------------
__global__ __launch_bounds__(256) void pv_fused(
    const int* __restrict__ adj,
    const float* __restrict__ el,
    const float* __restrict__ er,
    const unsigned short* __restrict__ hT,   // 256 x 16384
    float* __restrict__ out)
{
    __shared__ float er_s[1024];
    __shared__ float el_s[32];
    __shared__ float c_s[32];
    __shared__ __align__(16) unsigned short pk_s[32 * 64];     // 4 KB
    __shared__ __align__(16) unsigned char buf[8192];          // nibs / Ps
    __shared__ __align__(16) unsigned short Hs[256 * 64];      // 32 KB

    unsigned char (*nibs)[256] = (unsigned char (*)[256])buf;
    unsigned short* Ps = (unsigned short*)buf;                 // 32 x 72

    const int tid = threadIdx.x;
    const int w = tid >> 6, l = tid & 63;
    const int q = l >> 4, ml = l & 15;
    const int b = blockIdx.y;
    const int i0 = blockIdx.x * 32;

    *(float4*)(er_s + tid * 4) = *(const float4*)(er + (b << 10) + tid * 4);
    if (tid < 32) el_s[tid] = el[(b << 10) + i0 + tid];
    __syncthreads();

    // ---- pass 1: adj sweep, 8 rows per wave ----
    const float NINF = -__builtin_inff();
    const float* erb = er + (b << 10);
    for (int rr = 0; rr < 8; ++rr) {
        const int row = w * 8 + rr;
        const int* arow = adj + (size_t)((b << 10) + i0 + row) * 1024;
        const float eli = el_s[row];

        int4 av[4]; float4 erv[4];
#pragma unroll
        for (int it = 0; it < 4; ++it) {
            const int j = it * 256 + l * 4;
            av[it]  = *(const int4*)(arow + j);
            erv[it] = *(const float4*)(erb + j);
        }
        float s = 0.f;
#pragma unroll
        for (int it = 0; it < 4; ++it) {
            float e0 = eli + erv[it].x; e0 = e0 > 0.f ? e0 : ALPHA * e0;
            float e1 = eli + erv[it].y; e1 = e1 > 0.f ? e1 : ALPHA * e1;
            float e2 = eli + erv[it].z; e2 = e2 > 0.f ? e2 : ALPHA * e2;
            float e3 = eli + erv[it].w; e3 = e3 > 0.f ? e3 : ALPHA * e3;
            e0 = av[it].x > 0 ? e0 : NINF;
            e1 = av[it].y > 0 ? e1 : NINF;
            e2 = av[it].z > 0 ? e2 : NINF;
            e3 = av[it].w > 0 ? e3 : NINF;
            s += __expf(e0) + __expf(e1) + __expf(e2) + __expf(e3);
            nibs[row][it * 64 + l] =
                (unsigned char)((av[it].x > 0) | ((av[it].y > 0) << 1) |
                                ((av[it].z > 0) << 2) | ((av[it].w > 0) << 3));
        }
#pragma unroll
        for (int off = 32; off >= 1; off >>= 1) s += __shfl_xor(s, off);
        if (l == 0) c_s[row] = __logf(s);
    }
    // repack nibbles -> 16-bit words (wave-local rows; in-order LDS per wave)
    for (int rr = 0; rr < 8; ++rr) {
        const int row = w * 8 + rr;
        const unsigned nr = *(const unsigned int*)(&nibs[row][l * 4]);
        pk_s[row * 64 + l] =
            (unsigned short)((nr & 0xFu) | ((nr >> 4) & 0xF0u) |
                             ((nr >> 8) & 0xF00u) | ((nr >> 12) & 0xF000u));
    }
    __syncthreads();

    // ---- pass 2: MFMA j-loop ----
    const int ib = tid >> 3;
    const int js = (tid & 7) * 8;
    const float eli_b = el_s[ib];
    const float ci = c_s[ib];

    f32x4 acc[2][4];
    for (int i = 0; i < 2; ++i)
        for (int j = 0; j < 4; ++j) {
            f32x4 z = {0.f, 0.f, 0.f, 0.f};
            acc[i][j] = z;
        }

    const unsigned short* hb = hT + (size_t)b * 1024;

    for (int j0 = 0; j0 < 1024; j0 += 64) {
        for (int cr = 0; cr < 8; ++cr) {
            const int cb = cr * 256 + (w << 6);
            const int p = cb + l;
            const int r = p >> 3;
            const int cc = (p & 7) ^ (r & 7);
            gload_lds16(hb + (size_t)r * 16384 + j0 + cc * 8, Hs + cb * 8);
        }
        {
            const unsigned hw = pk_s[ib * 64 + ((j0 + js) >> 4)];
            const unsigned v = (hw >> ((j0 + js) & 15)) & 0xFFu;
            u16x8 pvv;
#pragma unroll
            for (int u = 0; u < 8; ++u) {
                float e = eli_b + er_s[j0 + js + u];
                e = e > 0.f ? e : ALPHA * e;
                const float p = ((v >> u) & 1u) ? __expf(e - ci) : 0.f;
                pvv[u] = f2bf(p);
            }
            *(u16x8*)(Ps + ib * 72 + js) = pvv;
        }
        __syncthreads();

        bf16x8 aF[2][2], bF[2][4];
#pragma unroll
        for (int ks = 0; ks < 2; ++ks) {
#pragma unroll
            for (int mt = 0; mt < 2; ++mt)
                aF[ks][mt] = *(const bf16x8*)(Ps + (mt * 16 + ml) * 72 + ks * 32 + q * 8);
#pragma unroll
            for (int nt = 0; nt < 4; ++nt) {
                const int oc = (w << 6) + nt * 16 + ml;
                bF[ks][nt] = *(const bf16x8*)(Hs + (oc * 8 + ((ks * 4 + q) ^ (oc & 7))) * 8);
            }
        }
#pragma unroll
        for (int ks = 0; ks < 2; ++ks)
            for (int mt = 0; mt < 2; ++mt)
                for (int nt = 0; nt < 4; ++nt)
                    acc[mt][nt] = __builtin_amdgcn_mfma_f32_16x16x32_bf16(
                        aF[ks][mt], bF[ks][nt], acc[mt][nt], 0, 0, 0);
        __syncthreads();
    }

    float* ob = out + (size_t)b * 262144;
    for (int mt = 0; mt < 2; ++mt)
        for (int nt = 0; nt < 4; ++nt) {
            const int gn = (w << 6) + nt * 16 + ml;
            for (int r = 0; r < 4; ++r) {
                const int gm = i0 + mt * 16 + q * 4 + r;
                ob[(size_t)gm * 256 + gn] = acc[mt][nt][r];
            }
        }
}

// ---------------------------------------------------------------------------
// Workspace (~8.65 MB):
//   Wtbf (bf16) @ 0       : 131072
//   wa   (f32)  @ 131072  : 2048
//   h_T  (bf16) @ 133120  : 8388608   (256 x 16384)
//   el   (f32)  @ 8521728 : 65536
//   er   (f32)  @ 8587264 : 65536
// ---------------------------------------------------------------------------
extern "C" void kernel_launch(void* const* d_in, const int* in_sizes, int n_in,
                              void* d_out, int out_size, void* d_ws, size_t ws_size,
                              hipStream_t stream) {
    const float* x   = (const float*)d_in[0];   // (16,1024,256) fp32
    const int*   adj = (const int*)d_in[1];     // (16,1024,1024) int32
    const float* W   = (const float*)d_in[2];   // (256,256) fp32
    const float* a   = (const float*)d_in[3];   // (512,1) fp32
    float* out = (float*)d_out;                 // (16,1024,256) fp32

    char* ws = (char*)d_ws;
    unsigned short* Wtbf = (unsigned short*)(ws);
    float* wa            = (float*)(ws + 131072);
    unsigned short* h_T  = (unsigned short*)(ws + 133120);
    float* el            = (float*)(ws + 8521728);
    float* er            = (float*)(ws + 8587264);

    wt_wa_kernel<<<dim3(257), dim3(256), 0, stream>>>(W, a, Wtbf, wa);

    // h_T = Wtbf @ x^T (direct fp32 x), fused exact el/er
    gemm_hx<<<dim3(128, 4), dim3(256), 0, stream>>>(Wtbf, x, wa, h_T, el, er);

    // fused mask + PV
    pv_fused<<<dim3(32, 16), dim3(256), 0, stream>>>(adj, el, er, h_T, out);
}